// Round 15
// baseline (190.372 us; speedup 1.0000x reference)
//
#include <hip/hip_runtime.h>

using half8   = __attribute__((ext_vector_type(8))) _Float16;
using f32x16  = __attribute__((ext_vector_type(16))) float;
using ushort8 = __attribute__((ext_vector_type(8))) unsigned short;

__device__ __forceinline__ void gload16(const void* g, void* l) {
  __builtin_amdgcn_global_load_lds(
      (const __attribute__((address_space(1))) void*)g,
      (__attribute__((address_space(3))) void*)l, 16, 0, 0);
}

// XCD-aware bijective swizzle with 8x4 2D rects. Requires gx%8==0, gy%4==0.
__device__ __forceinline__ void xcd_swizzle(int& x, int& y, int& z) {
  const int gx = gridDim.x, gy = gridDim.y;
  const int nwg = gx * gy * gridDim.z;
  const int f = blockIdx.x + gx * (blockIdx.y + gy * blockIdx.z);
  const int w = (f & 7) * (nwg >> 3) + (f >> 3);
  const int r = w >> 5, u = w & 31;
  const int nrx = gx >> 3, nry = gy >> 2;
  const int pz  = nrx * nry;
  const int rz  = r / pz, rr = r % pz;
  x = (rr % nrx) * 8 + (u & 7);
  y = (rr / nrx) * 4 + (u >> 3);
  z = rz;
}

// ---------------- cast fp32 -> fp16 ----------------
__global__ __launch_bounds__(256) void cast_f32_f16(
    const float* __restrict__ in, unsigned short* __restrict__ out, long n) {
  long i = ((long)blockIdx.x * 256 + threadIdx.x) * 8;
  if (i >= n) return;
  float4 a = *(const float4*)(in + i);
  float4 b = *(const float4*)(in + i + 4);
  union { _Float16 h[8]; ushort8 u; } r;
  r.h[0] = (_Float16)a.x; r.h[1] = (_Float16)a.y;
  r.h[2] = (_Float16)a.z; r.h[3] = (_Float16)a.w;
  r.h[4] = (_Float16)b.x; r.h[5] = (_Float16)b.y;
  r.h[6] = (_Float16)b.z; r.h[7] = (_Float16)b.w;
  *(ushort8*)(out + i) = r.u;
}

// ======== 32x32x16-MFMA NT GEMM: C[M,N] = A[M,K]*B[N,K]^T ========
// BM=BN=128, BK=64, 256 threads (2Mx2N waves), per-wave 64x64 = 2x2 of
// 32x32x16 f16 MFMA. Structure = R9 (dbuf LDS 64KB, 2 blocks/CU, one
// vmcnt(0)+barrier per tile, stage-early). CHANGE: MFMA shape 32x32x16
// halves the per-wave instruction chain (16 vs 32 MFMA, 2 vs 4 dependent
// clusters) at 1.19x higher pipe ceiling; fragment bytes identical.
// Operand frag (A and B): lane holds 8 contiguous k at row/col = lane&31,
// k-base = (lane>>5)*8 -> logical granule 2*ks+(lane>>5); stored granule =
// logical ^ (row&7) (same staging layout as R9; lanes 0-15 sweep 8 bank
// slots -> 2 lanes/bank, free). C/D: col=lane&31,
// row=(reg&3)+8*(reg>>2)+4*(lane>>5)  [m74/m101].
template <int MODE>
__global__ __launch_bounds__(256, 2) void gemm32(
    const unsigned short* __restrict__ Ab, const unsigned short* __restrict__ Bb,
    int K, int lda, int ldb, long sA, long sB,
    void* __restrict__ o0, void* __restrict__ o1, void* __restrict__ o2) {
  constexpr int ASZ = 128 * 64;                  // halves per slot (16 KB)
  constexpr int BSZ = 128 * 64;
  __shared__ unsigned short lds[2 * ASZ + 2 * BSZ];  // 64 KB

  const int tid  = threadIdx.x;
  const int lane = tid & 63;
  const int wv   = tid >> 6;
  const int wr   = wv >> 1, wc = wv & 1;
  const int lr   = lane & 31, lh = lane >> 5;
  int bxi, byi, bzi;
  xcd_swizzle(bxi, byi, bzi);
  const int bm = byi * 128;
  const int bn = bxi * 128;
  const int bz = bzi;

  const unsigned short* A = Ab + (long)bz * sA;
  const unsigned short* B = Bb + (long)bz * sB;

  // staging: thread t -> row tid>>3 per 32-row unit, granule tid&7,
  // source pre-swizzled: granule (tid&7)^(row&7) (gload_lds writes linearly)
  const int row_s = tid >> 3;
  const int col_s = ((tid & 7) ^ (row_s & 7)) * 8;
  const unsigned short* aS = A + (long)(bm + row_s) * lda + col_s;
  const unsigned short* bS = B + (long)(bn + row_s) * ldb + col_s;
  unsigned short* ldsA = lds;
  unsigned short* ldsB = lds + 2 * ASZ;

  // fragment read offsets (bytes): frag row = base + lr (base%32==0) ->
  // row&7 == lr&7; logical granule = 2*ks + lh, stored = logical ^ (lr&7)
  const int kg0 = ((0 + lh) ^ (lr & 7)) * 16;
  const int kg1 = ((2 + lh) ^ (lr & 7)) * 16;
  const int kg2 = ((4 + lh) ^ (lr & 7)) * 16;
  const int kg3 = ((6 + lh) ^ (lr & 7)) * 16;
  const int aRd = (wr * 64 + lr) * 128;   // + mi*4096 + kg
  const int bRd = (wc * 64 + lr) * 128;   // + ni*4096 + kg

  f32x16 acc[2][2] = {};
  half8 bf[2][4];                 // [ni][ks]
  half8 aF0, aF1, aF2, aF3;       // A frags, one mi at a time

  const int nt = K / 64;

#define STAGE_T(SL, T)                                                             \
  {                                                                                \
    const long kt = (long)(T) * 64;                                                \
    unsigned short* dA = ldsA + (SL) * ASZ + wv * 512;                             \
    unsigned short* dB = ldsB + (SL) * BSZ + wv * 512;                             \
    _Pragma("unroll") for (int i = 0; i < 4; ++i)                                  \
      gload16(aS + (long)(i * 32) * lda + kt, dA + i * 2048);                      \
    _Pragma("unroll") for (int i = 0; i < 4; ++i)                                  \
      gload16(bS + (long)(i * 32) * ldb + kt, dB + i * 2048);                      \
  }
#define RDA(MI)                                                                    \
  aF0 = *(const half8*)(lA + aRd + (MI) * 4096 + kg0);                             \
  aF1 = *(const half8*)(lA + aRd + (MI) * 4096 + kg1);                             \
  aF2 = *(const half8*)(lA + aRd + (MI) * 4096 + kg2);                             \
  aF3 = *(const half8*)(lA + aRd + (MI) * 4096 + kg3);
#define MFMAT(MI)                                                                  \
  _Pragma("unroll") for (int ni = 0; ni < 2; ++ni) {                               \
    acc[MI][ni] = __builtin_amdgcn_mfma_f32_32x32x16_f16(aF0, bf[ni][0],           \
                                                         acc[MI][ni], 0, 0, 0);   \
    acc[MI][ni] = __builtin_amdgcn_mfma_f32_32x32x16_f16(aF1, bf[ni][1],           \
                                                         acc[MI][ni], 0, 0, 0);   \
    acc[MI][ni] = __builtin_amdgcn_mfma_f32_32x32x16_f16(aF2, bf[ni][2],           \
                                                         acc[MI][ni], 0, 0, 0);   \
    acc[MI][ni] = __builtin_amdgcn_mfma_f32_32x32x16_f16(aF3, bf[ni][3],           \
                                                         acc[MI][ni], 0, 0, 0);   \
  }

  // ---- prologue: stage tile 0 into slot 0 ----
  STAGE_T(0, 0)
  asm volatile("s_waitcnt vmcnt(0)" ::: "memory");
  __builtin_amdgcn_s_barrier();
  __builtin_amdgcn_sched_barrier(0);

  for (int tt = 0; tt < nt; ++tt) {
    const int sl = tt & 1;
    const char* lA = (const char*)(ldsA + sl * ASZ);
    const char* lB = (const char*)(ldsB + sl * BSZ);
#pragma unroll
    for (int ni = 0; ni < 2; ++ni) {
      bf[ni][0] = *(const half8*)(lB + bRd + ni * 4096 + kg0);
      bf[ni][1] = *(const half8*)(lB + bRd + ni * 4096 + kg1);
      bf[ni][2] = *(const half8*)(lB + bRd + ni * 4096 + kg2);
      bf[ni][3] = *(const half8*)(lB + bRd + ni * 4096 + kg3);
    }
    RDA(0)
    if (tt + 1 < nt) STAGE_T(sl ^ 1, tt + 1)
    MFMAT(0)
    RDA(1)
    MFMAT(1)
    asm volatile("s_waitcnt vmcnt(0)" ::: "memory");
    __builtin_amdgcn_s_barrier();
    __builtin_amdgcn_sched_barrier(0);
  }
#undef STAGE_T
#undef RDA
#undef MFMAT

  // epilogue: 32x32 C/D layout col=lane&31, row=(reg&3)+8*(reg>>2)+4*(lane>>5)
  const int row0 = bm + wr * 64 + lh * 4;
  const int col0 = bn + wc * 64 + lr;
#pragma unroll
  for (int mi = 0; mi < 2; ++mi) {
#pragma unroll
    for (int ni = 0; ni < 2; ++ni) {
      f32x16 c = acc[mi][ni];
      const long e = col0 + ni * 32;
#pragma unroll
      for (int reg = 0; reg < 16; ++reg) {
        const long i = row0 + mi * 32 + (reg & 3) + 8 * (reg >> 2);
        const float val = c[reg];
        if constexpr (MODE == 0) {
          _Float16* q  = (_Float16*)o0;
          _Float16* kk = (_Float16*)o1;
          _Float16* vv = (_Float16*)o2;
          if (e < 1024)      q [i * 1024 + e]          = (_Float16)(val * 0.03125f);
          else if (e < 2048) kk[i * 1024 + (e - 1024)] = (_Float16)val;
          else               vv[i * 1024 + (e - 2048)] = (_Float16)val;
        } else if constexpr (MODE == 1) {
          float* C = (float*)o0 + (long)bz * 2048 * 2048;
          C[i * 2048 + e] = val;
        } else {
          float* C = (float*)o0 + (long)bz * 2048 * 1024;
          C[i * 1024 + e] = val;
        }
      }
    }
  }
}

// ---------------- transpose v [b][n][d] -> vT [b][d][n] (fp16) ----------------
__global__ __launch_bounds__(256) void transpose_v(
    const unsigned short* __restrict__ v, unsigned short* __restrict__ vT) {
  __shared__ unsigned short t[64][72];  // +8 pad
  const long b = blockIdx.z;
  const unsigned short* vb = v + b * (2048L * 1024);
  unsigned short* ob = vT + b * (1024L * 2048);
  const int n0 = blockIdx.y * 64;
  const int d0 = blockIdx.x * 64;
  const int tid = threadIdx.x;
  const int r  = tid >> 2;
  const int c0 = (tid & 3) * 16;
  const unsigned short* src = vb + (long)(n0 + r) * 1024 + d0 + c0;
  *(ushort4*)&t[r][c0]      = *(const ushort4*)(src);
  *(ushort4*)&t[r][c0 + 4]  = *(const ushort4*)(src + 4);
  *(ushort4*)&t[r][c0 + 8]  = *(const ushort4*)(src + 8);
  *(ushort4*)&t[r][c0 + 12] = *(const ushort4*)(src + 12);
  __syncthreads();
  union { unsigned short h[8]; ushort8 u; } w0, w1;
#pragma unroll
  for (int j = 0; j < 8; ++j) w0.h[j] = t[c0 + j][r];
#pragma unroll
  for (int j = 0; j < 8; ++j) w1.h[j] = t[c0 + 8 + j][r];
  unsigned short* dst = ob + (long)(d0 + r) * 2048 + n0 + c0;
  *(ushort8*)dst       = w0.u;
  *(ushort8*)(dst + 8) = w1.u;
}

// ---------------- row softmax fp32[2048] -> fp16 in-place ----------------
__global__ __launch_bounds__(256) void softmax_rows(float* __restrict__ S) {
  const long row = blockIdx.x;
  float* p = S + row * 2048;
  const int t = threadIdx.x;
  float4 v0 = *(const float4*)(p + t * 8);
  float4 v1 = *(const float4*)(p + t * 8 + 4);
  float f[8] = {v0.x, v0.y, v0.z, v0.w, v1.x, v1.y, v1.z, v1.w};
  float m = f[0];
#pragma unroll
  for (int j = 1; j < 8; ++j) m = fmaxf(m, f[j]);
  for (int o = 32; o; o >>= 1) m = fmaxf(m, __shfl_xor(m, o));
  __shared__ float redm[4];
  if (!(t & 63)) redm[t >> 6] = m;
  __syncthreads();
  m = fmaxf(fmaxf(redm[0], redm[1]), fmaxf(redm[2], redm[3]));
  float e[8], s = 0.f;
#pragma unroll
  for (int j = 0; j < 8; ++j) { e[j] = __expf(f[j] - m); s += e[j]; }
  for (int o = 32; o; o >>= 1) s += __shfl_xor(s, o);
  __shared__ float reds[4];
  if (!(t & 63)) reds[t >> 6] = s;
  __syncthreads();
  s = reds[0] + reds[1] + reds[2] + reds[3];
  const float inv = 1.0f / s;
  union { _Float16 h[8]; ushort8 u; } r;
#pragma unroll
  for (int j = 0; j < 8; ++j) r.h[j] = (_Float16)(e[j] * inv);
  *(ushort8*)((unsigned short*)p + t * 8) = r.u;  // P fp16, row pitch 4096 halves
}

extern "C" void kernel_launch(void* const* d_in, const int* in_sizes, int n_in,
                              void* d_out, int out_size, void* d_ws, size_t ws_size,
                              hipStream_t stream) {
  const float* x = (const float*)d_in[0];   // [4,2048,1024]
  const float* W = (const float*)d_in[1];   // [3072,1024]
  float* out = (float*)d_out;               // [4,2048,1024] fp32
  char* ws = (char*)d_ws;

  const long MB16 = 16777216;  // 8192*1024*2 bytes
  unsigned short* q  = (unsigned short*)(ws);
  unsigned short* k  = (unsigned short*)(ws + MB16);
  unsigned short* vT = (unsigned short*)(ws + 2 * MB16);
  float*          S  = (float*)(ws + 3 * MB16);              // 64 MiB
  // aliased into S region (dead before S is written):
  unsigned short* xb = (unsigned short*)(ws + 3 * MB16);
  unsigned short* wb = (unsigned short*)(ws + 4 * MB16);
  unsigned short* v  = (unsigned short*)(ws + 4 * MB16 + 6291456);

  // 1. casts
  cast_f32_f16<<<4096, 256, 0, stream>>>(x, xb, 8388608L);
  cast_f32_f16<<<1536, 256, 0, stream>>>(W, wb, 3145728L);
  // 2. qkv = x @ W^T (M=8192, N=3072, K=1024): 24x64 = 1536 blocks (3 rounds)
  gemm32<0><<<dim3(24, 64, 1), 256, 0, stream>>>(
      xb, wb, 1024, 1024, 1024, 0L, 0L, q, k, v);
  // 3. v -> vT per batch
  transpose_v<<<dim3(16, 32, 4), 256, 0, stream>>>(v, vT);
  // 4. S = (q*scale) @ k^T per batch (M=N=2048, K=1024): 16x16x4 = 1024 blocks
  gemm32<1><<<dim3(16, 16, 4), 256, 0, stream>>>(
      q, k, 1024, 1024, 1024, 2048L * 1024, 2048L * 1024, S, nullptr, nullptr);
  // 5. row softmax, P fp16 in place (row pitch 4096 halves)
  softmax_rows<<<8192, 256, 0, stream>>>(S);
  // 6. out = P @ vT^T per batch (M=2048, N=1024, K=2048): 8x16x4 = 512 blocks
  gemm32<2><<<dim3(8, 16, 4), 256, 0, stream>>>(
      (unsigned short*)S, vT, 2048, 4096, 2048, 2048L * 4096, 1024L * 2048,
      out, nullptr, nullptr);
}

// Round 16
// 166.787 us; speedup vs baseline: 1.1414x; 1.1414x over previous
//
#include <hip/hip_runtime.h>

using half8   = __attribute__((ext_vector_type(8))) _Float16;
using f32x4   = __attribute__((ext_vector_type(4))) float;
using ushort8 = __attribute__((ext_vector_type(8))) unsigned short;

__device__ __forceinline__ void gload16(const void* g, void* l) {
  __builtin_amdgcn_global_load_lds(
      (const __attribute__((address_space(1))) void*)g,
      (__attribute__((address_space(3))) void*)l, 16, 0, 0);
}

// XCD-aware bijective swizzle with 8x4 2D rects. Requires gx%8==0, gy%4==0.
__device__ __forceinline__ void xcd_swizzle(int& x, int& y, int& z) {
  const int gx = gridDim.x, gy = gridDim.y;
  const int nwg = gx * gy * gridDim.z;
  const int f = blockIdx.x + gx * (blockIdx.y + gy * blockIdx.z);
  const int w = (f & 7) * (nwg >> 3) + (f >> 3);
  const int r = w >> 5, u = w & 31;
  const int nrx = gx >> 3, nry = gy >> 2;
  const int pz  = nrx * nry;
  const int rz  = r / pz, rr = r % pz;
  x = (rr % nrx) * 8 + (u & 7);
  y = (rr / nrx) * 4 + (u >> 3);
  z = rz;
}

// ---------------- cast fp32 -> fp16 ----------------
__global__ __launch_bounds__(256) void cast_f32_f16(
    const float* __restrict__ in, unsigned short* __restrict__ out, long n) {
  long i = ((long)blockIdx.x * 256 + threadIdx.x) * 8;
  if (i >= n) return;
  float4 a = *(const float4*)(in + i);
  float4 b = *(const float4*)(in + i + 4);
  union { _Float16 h[8]; ushort8 u; } r;
  r.h[0] = (_Float16)a.x; r.h[1] = (_Float16)a.y;
  r.h[2] = (_Float16)a.z; r.h[3] = (_Float16)a.w;
  r.h[4] = (_Float16)b.x; r.h[5] = (_Float16)b.y;
  r.h[6] = (_Float16)b.z; r.h[7] = (_Float16)b.w;
  *(ushort8*)(out + i) = r.u;
}

// ======== R9 gemm4w (best total: 171 us), MODE-1 epilogue now fp16 ========
// BM=BN=128, BK=64, 256 threads (2Mx2N waves), per-wave 64x64 (4x4 of
// 16x16x32 f16). LDS 64KB dbuf -> 2 blocks/CU. One vmcnt(0)+barrier per tile;
// stage t+1 issued early (drain distance = full tile >> HBM latency); compiler
// inserts counted lgkm waits between quadrant reads and MFMAs.
// MODE 0: split q(scaled)/k/v fp16.  MODE 1: fp16 C, ldc=2048 (S16 logits --
// bounded ~N(0,1), fp16-safe; halves S write + softmax read traffic).
// MODE 2: fp32 C, ldc=1024.
template <int MODE>
__global__ __launch_bounds__(256, 2) void gemm4w(
    const unsigned short* __restrict__ Ab, const unsigned short* __restrict__ Bb,
    int K, int lda, int ldb, long sA, long sB,
    void* __restrict__ o0, void* __restrict__ o1, void* __restrict__ o2) {
  constexpr int ASZ = 128 * 64;  // halves per slot
  constexpr int BSZ = 128 * 64;
  __shared__ unsigned short lds[2 * ASZ + 2 * BSZ];  // 64 KB

  const int tid  = threadIdx.x;
  const int lane = tid & 63;
  const int wv   = tid >> 6;
  const int wr   = wv >> 1, wc = wv & 1;
  const int fr   = lane & 15, fq = lane >> 4;
  int bxi, byi, bzi;
  xcd_swizzle(bxi, byi, bzi);
  const int bm = byi * 128;
  const int bn = bxi * 128;
  const int bz = bzi;

  const unsigned short* A = Ab + (long)bz * sA;
  const unsigned short* B = Bb + (long)bz * sB;

  // staging: thread t -> row tid>>3 per 32-row issue, granule tid&7,
  // source pre-swizzled (gload_lds writes linearly; reads apply same XOR)
  const int row_s = tid >> 3;
  const int col_s = ((tid & 7) ^ (row_s & 7)) * 8;
  const unsigned short* aS = A + (long)(bm + row_s) * lda + col_s;
  const unsigned short* bS = B + (long)(bn + row_s) * ldb + col_s;
  unsigned short* ldsA = lds;
  unsigned short* ldsB = lds + 2 * ASZ;

  // read offsets (bytes); all frag rows have row&7 == fr&7
  const int kg0 = ((0 * 4 + fq) ^ (fr & 7)) * 16;
  const int kg1 = ((1 * 4 + fq) ^ (fr & 7)) * 16;
  const int aRd = (wr * 64 + fr) * 128;  // + mi*2048 + kg
  const int bRd = (wc * 64 + fr) * 128;  // + ni*2048 + kg

  f32x4 acc[4][4] = {};
  half8 bf[4][2];
  half8 a0[2], a1[2], a2[2], a3[2];

  const int nt = K / 64;

#define STAGE_T(SL, T)                                                             \
  {                                                                                \
    const long kt = (long)(T) * 64;                                                \
    unsigned short* dA = ldsA + (SL) * ASZ + wv * 512;                             \
    unsigned short* dB = ldsB + (SL) * BSZ + wv * 512;                             \
    _Pragma("unroll") for (int i = 0; i < 4; ++i)                                  \
      gload16(aS + (long)(i * 32) * lda + kt, dA + i * 2048);                      \
    _Pragma("unroll") for (int i = 0; i < 4; ++i)                                  \
      gload16(bS + (long)(i * 32) * ldb + kt, dB + i * 2048);                      \
  }
#define RDA(DST, MI)                                                               \
  DST[0] = *(const half8*)(lA + aRd + (MI) * 2048 + kg0);                          \
  DST[1] = *(const half8*)(lA + aRd + (MI) * 2048 + kg1);
#define MFMAQ(MI, AA)                                                              \
  __builtin_amdgcn_s_setprio(1);                                                   \
  _Pragma("unroll") for (int ks = 0; ks < 2; ++ks)                                 \
  _Pragma("unroll") for (int ni = 0; ni < 4; ++ni)                                 \
    acc[MI][ni] = __builtin_amdgcn_mfma_f32_16x16x32_f16(                          \
        AA[ks], bf[ni][ks], acc[MI][ni], 0, 0, 0);                                 \
  __builtin_amdgcn_s_setprio(0);

  // ---- prologue: stage tile 0 into slot 0 ----
  STAGE_T(0, 0)
  asm volatile("s_waitcnt vmcnt(0)" ::: "memory");
  __builtin_amdgcn_s_barrier();
  __builtin_amdgcn_sched_barrier(0);

  for (int tt = 0; tt < nt; ++tt) {
    const int sl = tt & 1;
    const char* lA = (const char*)(ldsA + sl * ASZ);
    const char* lB = (const char*)(ldsB + sl * BSZ);
#pragma unroll
    for (int ni = 0; ni < 4; ++ni) {
      bf[ni][0] = *(const half8*)(lB + bRd + ni * 2048 + kg0);
      bf[ni][1] = *(const half8*)(lB + bRd + ni * 2048 + kg1);
    }
    RDA(a0, 0)
    RDA(a1, 1)
    if (tt + 1 < nt) STAGE_T(sl ^ 1, tt + 1)
    MFMAQ(0, a0)
    RDA(a2, 2)
    MFMAQ(1, a1)
    RDA(a3, 3)
    MFMAQ(2, a2)
    MFMAQ(3, a3)
    asm volatile("s_waitcnt vmcnt(0)" ::: "memory");
    __builtin_amdgcn_s_barrier();
    __builtin_amdgcn_sched_barrier(0);
  }
#undef STAGE_T
#undef RDA
#undef MFMAQ

  // epilogue: C/D layout col=lane&15, row=fq*4+reg
  const int row0 = bm + wr * 64 + fq * 4;
  const int col0 = bn + wc * 64 + fr;
#pragma unroll
  for (int mi = 0; mi < 4; ++mi) {
#pragma unroll
    for (int ni = 0; ni < 4; ++ni) {
      f32x4 c = acc[mi][ni];
      const long r0 = row0 + mi * 16;
      const long e  = col0 + ni * 16;
      if constexpr (MODE == 0) {
        _Float16* q  = (_Float16*)o0;
        _Float16* kk = (_Float16*)o1;
        _Float16* vv = (_Float16*)o2;
#pragma unroll
        for (int j = 0; j < 4; ++j) {
          const long i = r0 + j;
          const float val = c[j];
          if (e < 1024)      q [i * 1024 + e]          = (_Float16)(val * 0.03125f);
          else if (e < 2048) kk[i * 1024 + (e - 1024)] = (_Float16)val;
          else               vv[i * 1024 + (e - 2048)] = (_Float16)val;
        }
      } else if constexpr (MODE == 1) {
        _Float16* C = (_Float16*)o0 + (long)bz * 2048 * 2048;
#pragma unroll
        for (int j = 0; j < 4; ++j) C[(r0 + j) * 2048 + e] = (_Float16)c[j];
      } else {
        float* C = (float*)o0 + (long)bz * 2048 * 1024;
#pragma unroll
        for (int j = 0; j < 4; ++j) C[(r0 + j) * 1024 + e] = c[j];
      }
    }
  }
}

// ---------------- transpose v [b][n][d] -> vT [b][d][n] (fp16) ----------------
__global__ __launch_bounds__(256) void transpose_v(
    const unsigned short* __restrict__ v, unsigned short* __restrict__ vT) {
  __shared__ unsigned short t[64][72];  // +8 pad
  const long b = blockIdx.z;
  const unsigned short* vb = v + b * (2048L * 1024);
  unsigned short* ob = vT + b * (1024L * 2048);
  const int n0 = blockIdx.y * 64;
  const int d0 = blockIdx.x * 64;
  const int tid = threadIdx.x;
  const int r  = tid >> 2;
  const int c0 = (tid & 3) * 16;
  const unsigned short* src = vb + (long)(n0 + r) * 1024 + d0 + c0;
  *(ushort4*)&t[r][c0]      = *(const ushort4*)(src);
  *(ushort4*)&t[r][c0 + 4]  = *(const ushort4*)(src + 4);
  *(ushort4*)&t[r][c0 + 8]  = *(const ushort4*)(src + 8);
  *(ushort4*)&t[r][c0 + 12] = *(const ushort4*)(src + 12);
  __syncthreads();
  union { unsigned short h[8]; ushort8 u; } w0, w1;
#pragma unroll
  for (int j = 0; j < 8; ++j) w0.h[j] = t[c0 + j][r];
#pragma unroll
  for (int j = 0; j < 8; ++j) w1.h[j] = t[c0 + 8 + j][r];
  unsigned short* dst = ob + (long)(d0 + r) * 2048 + n0 + c0;
  *(ushort8*)dst       = w0.u;
  *(ushort8*)(dst + 8) = w1.u;
}

// -------- row softmax fp16[2048] -> fp16 in place --------
__global__ __launch_bounds__(256) void softmax_rows_f16(unsigned short* __restrict__ S) {
  const long row = blockIdx.x;
  unsigned short* p = S + row * 2048;
  const int t = threadIdx.x;
  union { ushort8 u; _Float16 h[8]; } in;
  in.u = *(const ushort8*)(p + t * 8);
  float f[8];
#pragma unroll
  for (int j = 0; j < 8; ++j) f[j] = (float)in.h[j];
  float m = f[0];
#pragma unroll
  for (int j = 1; j < 8; ++j) m = fmaxf(m, f[j]);
  for (int o = 32; o; o >>= 1) m = fmaxf(m, __shfl_xor(m, o));
  __shared__ float redm[4];
  if (!(t & 63)) redm[t >> 6] = m;
  __syncthreads();  // also ensures all loads done before in-place store
  m = fmaxf(fmaxf(redm[0], redm[1]), fmaxf(redm[2], redm[3]));
  float e[8], s = 0.f;
#pragma unroll
  for (int j = 0; j < 8; ++j) { e[j] = __expf(f[j] - m); s += e[j]; }
  for (int o = 32; o; o >>= 1) s += __shfl_xor(s, o);
  __shared__ float reds[4];
  if (!(t & 63)) reds[t >> 6] = s;
  __syncthreads();
  s = reds[0] + reds[1] + reds[2] + reds[3];
  const float inv = 1.0f / s;
  union { _Float16 h[8]; ushort8 u; } r;
#pragma unroll
  for (int j = 0; j < 8; ++j) r.h[j] = (_Float16)(e[j] * inv);
  *(ushort8*)(p + t * 8) = r.u;
}

extern "C" void kernel_launch(void* const* d_in, const int* in_sizes, int n_in,
                              void* d_out, int out_size, void* d_ws, size_t ws_size,
                              hipStream_t stream) {
  const float* x = (const float*)d_in[0];   // [4,2048,1024]
  const float* W = (const float*)d_in[1];   // [3072,1024]
  float* out = (float*)d_out;               // [4,2048,1024] fp32
  char* ws = (char*)d_ws;

  const long MB = 1048576;
  unsigned short* q   = (unsigned short*)(ws);              //  0..16 MiB
  unsigned short* k   = (unsigned short*)(ws + 16 * MB);    // 16..32
  unsigned short* vT  = (unsigned short*)(ws + 32 * MB);    // 32..48
  unsigned short* S16 = (unsigned short*)(ws + 48 * MB);    // 48..80 (fp16 S/P)
  // aliased into the S16 region (all dead before S16 is written):
  unsigned short* xb = (unsigned short*)(ws + 48 * MB);     // 48..64
  unsigned short* wb = (unsigned short*)(ws + 64 * MB);     // 64..70
  unsigned short* v  = (unsigned short*)(ws + 70 * MB);     // 70..86
  // peak ws usage: 86 MiB

  // 1. casts
  cast_f32_f16<<<4096, 256, 0, stream>>>(x, xb, 8388608L);
  cast_f32_f16<<<1536, 256, 0, stream>>>(W, wb, 3145728L);
  // 2. qkv = x @ W^T (M=8192, N=3072, K=1024): 24x64 = 1536 blocks
  gemm4w<0><<<dim3(24, 64, 1), 256, 0, stream>>>(
      xb, wb, 1024, 1024, 1024, 0L, 0L, q, k, v);
  // 3. v -> vT per batch
  transpose_v<<<dim3(16, 32, 4), 256, 0, stream>>>(v, vT);
  // 4. S = (q*scale) @ k^T per batch (M=N=2048, K=1024), fp16 out: 1024 blocks
  gemm4w<1><<<dim3(16, 16, 4), 256, 0, stream>>>(
      q, k, 1024, 1024, 1024, 2048L * 1024, 2048L * 1024, S16, nullptr, nullptr);
  // 5. row softmax fp16 in place
  softmax_rows_f16<<<8192, 256, 0, stream>>>(S16);
  // 6. out = P @ vT^T per batch (M=2048, N=1024, K=2048): 512 blocks
  gemm4w<2><<<dim3(8, 16, 4), 256, 0, stream>>>(
      S16, vT, 2048, 2048, 2048, 2048L * 2048, 1024L * 2048,
      out, nullptr, nullptr);
}